// Round 11
// baseline (208.189 us; speedup 1.0000x reference)
//
#include <hip/hip_runtime.h>
#include <math.h>

// Shapes: B=8, H=W=64, C=256, HEADS=8, d=32, WS=8, SS=4, K=9
// Pipeline: prep (1 kernel) -> qkv (bf16 MFMA, v2: 128-row pipelined dbuf) ->
//           attn+proj fused (f16 MFMA) -> sample+conv (f16 MFMA, pipelined).

#define NFLOAT_BUF 8388608  // 32768*256

typedef float f32x4 __attribute__((ext_vector_type(4)));
typedef __bf16 bf16x8 __attribute__((ext_vector_type(8)));
typedef _Float16 f16x8 __attribute__((ext_vector_type(8)));

__device__ inline unsigned pack2_bf16(float a, float b) {
    union { float f; unsigned u; } ua, ub;
    ua.f = a; ub.f = b;
    unsigned ra = (ua.u + 0x7FFFu + ((ua.u >> 16) & 1u)) >> 16;
    unsigned rb = (ub.u + 0x7FFFu + ((ub.u >> 16) & 1u)) & 0xFFFF0000u;
    return (ra & 0xFFFFu) | rb;
}

// ---------------------------------------------------------------------------
// prep: all input conversions in ONE launch, partitioned by blockIdx.
// ---------------------------------------------------------------------------
__global__ __launch_bounds__(256) void prep_kernel(
    const float* __restrict__ x, unsigned short* __restrict__ xb,
    const float* __restrict__ qkv_w, unsigned short* __restrict__ wb,
    const float* __restrict__ proj_w, _Float16* __restrict__ pwh,
    const float* __restrict__ dsc_w, _Float16* __restrict__ wT,
    const float* __restrict__ offset, float* __restrict__ ymap) {
    int bid = blockIdx.x, tid = threadIdx.x;
    if (bid < 4096) {
        int t = bid * 256 + tid;
        const float4* s = (const float4*)(x + (size_t)t * 8);
        float4 a = s[0], b = s[1];
        uint4 o;
        o.x = pack2_bf16(a.x, a.y); o.y = pack2_bf16(a.z, a.w);
        o.z = pack2_bf16(b.x, b.y); o.w = pack2_bf16(b.z, b.w);
        *(uint4*)(xb + (size_t)t * 8) = o;
    } else if (bid < 4192) {
        int t = (bid - 4096) * 256 + tid;
        if (t < 24576) {
            const float4* s = (const float4*)(qkv_w + (size_t)t * 8);
            float4 a = s[0], b = s[1];
            uint4 o;
            o.x = pack2_bf16(a.x, a.y); o.y = pack2_bf16(a.z, a.w);
            o.z = pack2_bf16(b.x, b.y); o.w = pack2_bf16(b.z, b.w);
            *(uint4*)(wb + (size_t)t * 8) = o;
        }
    } else if (bid < 4224) {
        int t = (bid - 4192) * 256 + tid;
        if (t < 8192) {
            const float4* s = (const float4*)(proj_w + (size_t)t * 8);
            float4 a = s[0], b = s[1];
            union { _Float16 h[8]; uint4 u; } o;
            o.h[0] = (_Float16)a.x; o.h[1] = (_Float16)a.y;
            o.h[2] = (_Float16)a.z; o.h[3] = (_Float16)a.w;
            o.h[4] = (_Float16)b.x; o.h[5] = (_Float16)b.y;
            o.h[6] = (_Float16)b.z; o.h[7] = (_Float16)b.w;
            *(uint4*)(pwh + (size_t)t * 8) = o.u;
        }
    } else if (bid < 6528) {
        int t = (bid - 4224) * 256 + tid;   // < 589824
        int o = t / 2304;
        int kk = t - o * 2304;
        int k = kk >> 8, i = kk & 255;
        wT[t] = (_Float16)dsc_w[(o * 256 + i) * 9 + k];
    } else {
        int t = (bid - 6528) * 256 + tid;   // < 32768
        int hd = t & 63;
        int wd = (t >> 6) & 63;
        int b  = t >> 12;
        const float* op = offset + ((size_t)(b * 18) * 64 + wd) * 64 + hd;
        float yo[9];
        #pragma unroll
        for (int k = 0; k < 9; ++k) yo[k] = op[(size_t)k * 4096];
        float cum[9];
        cum[4] = 0.0f;
        float s = 0.0f;
        for (int j = 3; j >= 0; --j) { s += yo[j]; cum[j] = s; }
        s = 0.0f;
        for (int j = 5; j < 9; ++j) { s += yo[j]; cum[j] = s; }
        float wdf = (float)wd;
        float* yp = ymap + ((size_t)(b * 576 + wd * 9)) * 64 + hd;
        #pragma unroll
        for (int k = 0; k < 9; ++k) yp[(size_t)k * 64] = wdf + cum[k];
    }
}

// ---------------------------------------------------------------------------
// QKV GEMM v2 via bf16 MFMA — conv-v4 structure. Block = 128 rows x 256 N,
// 512 threads = 8 waves (2 row-half x 4 col-quarter). grid (3, 256), 1 blk/CU.
// Double-buffered A(2x16K)+B(2x32K); stages for c+1 issued before MFMA of c;
// one barrier/iter. Epilogue: q/k via swizzled 64KB LDS bounce -> uint4
// coalesced stores; v direct (uint2, transposed [d][l]).
// ---------------------------------------------------------------------------
__global__ __launch_bounds__(512, 2) void qkv_mfma2_kernel(
    const unsigned short* __restrict__ xb, const unsigned short* __restrict__ wb,
    const float* __restrict__ qkv_b,
    _Float16* __restrict__ qh, _Float16* __restrict__ kh, _Float16* __restrict__ vt) {

    __shared__ __align__(16) char SH[98816];
    char* Ab[2] = { SH, SH + 16384 };             // 128 rows * 128B each
    char* Bb[2] = { SH + 32768, SH + 65536 };     // 256 rows * 128B each
    unsigned* rowoff = (unsigned*)(SH + 98304);   // [128]

    int nb = blockIdx.x;           // 0..2 (q / k / v)
    int m0 = blockIdx.y * 128;
    int gw0 = m0 >> 6;             // first of two windows in this block
    int tid = threadIdx.x;
    int lane = tid & 63, w = tid >> 6;
    int qc = lane & 15, g = lane >> 4;
    int ph = w >> 2, nq = w & 3;   // row half, col quarter

    if (tid < 128) {
        int l = tid;
        int gw = gw0 + (l >> 6);
        int b = gw >> 6, win = gw & 63;
        int l2 = l & 63;
        int rh = ((win >> 3) << 3) + (l2 >> 3);
        int rw = ((win & 7) << 3) + (l2 & 7);
        int sh_ = (rh + 4) & 63, sw_ = (rw + 4) & 63;
        rowoff[l] = (unsigned)(((b * 64 + sh_) * 64 + sw_) * 512);  // byte offset
    }

    f32x4 acc[4][4];
    #pragma unroll
    for (int m = 0; m < 4; ++m)
        #pragma unroll
        for (int n = 0; n < 4; ++n) {
            f32x4 z = {0.0f, 0.0f, 0.0f, 0.0f};
            acc[m][n] = z;
        }

    const char* xc = (const char*)xb;
    const char* wc = (const char*)wb;
    int rAa = qc * 128;
    int u0 = ((g    ) ^ (qc & 7)) << 4;
    int u1 = ((4 + g) ^ (qc & 7)) << 4;

    __syncthreads();   // rowoff ready

    // prologue: stage c=0 into buf 0
    #pragma unroll
    for (int r = 0; r < 2; ++r) {          // A: 1024 slots / 512 thr
        int pos = r * 512 + tid;
        int row = pos >> 3, u = pos & 7;
        const char* src = xc + rowoff[row] + ((u ^ (row & 7)) << 4);
        __builtin_amdgcn_global_load_lds(
            (const __attribute__((address_space(1))) unsigned int*)src,
            (__attribute__((address_space(3))) unsigned int*)(Ab[0] + pos * 16),
            16, 0, 0);
    }
    #pragma unroll
    for (int r = 0; r < 4; ++r) {          // B: 2048 slots / 512 thr
        int pos = r * 512 + tid;
        int n = pos >> 3, u = pos & 7;
        const char* src = wc + (size_t)(nb * 256 + n) * 512 + ((u ^ (n & 7)) << 4);
        __builtin_amdgcn_global_load_lds(
            (const __attribute__((address_space(1))) unsigned int*)src,
            (__attribute__((address_space(3))) unsigned int*)(Bb[0] + pos * 16),
            16, 0, 0);
    }
    __syncthreads();

    for (int c = 0; c < 4; ++c) {
        int cur = c & 1, nxt = cur ^ 1;

        if (c < 3) {
            int cn = c + 1;
            #pragma unroll
            for (int r = 0; r < 2; ++r) {
                int pos = r * 512 + tid;
                int row = pos >> 3, u = pos & 7;
                const char* src = xc + rowoff[row] + cn * 128 + ((u ^ (row & 7)) << 4);
                __builtin_amdgcn_global_load_lds(
                    (const __attribute__((address_space(1))) unsigned int*)src,
                    (__attribute__((address_space(3))) unsigned int*)(Ab[nxt] + pos * 16),
                    16, 0, 0);
            }
            #pragma unroll
            for (int r = 0; r < 4; ++r) {
                int pos = r * 512 + tid;
                int n = pos >> 3, u = pos & 7;
                const char* src = wc + (size_t)(nb * 256 + n) * 512 + cn * 128 + ((u ^ (n & 7)) << 4);
                __builtin_amdgcn_global_load_lds(
                    (const __attribute__((address_space(1))) unsigned int*)src,
                    (__attribute__((address_space(3))) unsigned int*)(Bb[nxt] + pos * 16),
                    16, 0, 0);
            }
        }

        bf16x8 av[4][2], bv[4][2];
        #pragma unroll
        for (int m = 0; m < 4; ++m) {
            char* abase = Ab[cur] + ph * 8192 + m * 2048 + rAa;
            av[m][0] = *(const bf16x8*)(abase + u0);
            av[m][1] = *(const bf16x8*)(abase + u1);
        }
        #pragma unroll
        for (int n = 0; n < 4; ++n) {
            char* bbase = Bb[cur] + nq * 8192 + n * 2048 + rAa;
            bv[n][0] = *(const bf16x8*)(bbase + u0);
            bv[n][1] = *(const bf16x8*)(bbase + u1);
        }
        #pragma unroll
        for (int m = 0; m < 4; ++m)
            #pragma unroll
            for (int n = 0; n < 4; ++n) {
                acc[m][n] = __builtin_amdgcn_mfma_f32_16x16x32_bf16(av[m][0], bv[n][0], acc[m][n], 0, 0, 0);
                acc[m][n] = __builtin_amdgcn_mfma_f32_16x16x32_bf16(av[m][1], bv[n][1], acc[m][n], 0, 0, 0);
            }
        __syncthreads();
    }

    if (nb == 2) {
        // v: direct transposed write [win*8+h][d=32][l=64], uint2 chunks
        #pragma unroll
        for (int n = 0; n < 4; ++n) {
            int o = nq * 64 + n * 16 + qc;
            float bias = qkv_b[512 + o];
            int hh = o >> 5, dd = o & 31;
            _Float16* base = vt + ((size_t)((gw0 + ph) * 8 + hh) * 32 + dd) * 64;
            #pragma unroll
            for (int m = 0; m < 4; ++m) {
                int l0 = m * 16 + g * 4;
                union { _Float16 x[4]; uint2 u; } pk;
                #pragma unroll
                for (int j = 0; j < 4; ++j) pk.x[j] = (_Float16)(acc[m][n][j] + bias);
                *(uint2*)(base + l0) = pk.u;
            }
        }
    } else {
        // q/k: bounce through swizzled eL[128][256] f16 (64KB, reuse B area)
        float scale = (nb == 0) ? 0.17677669529663689f : 1.0f;
        char* eL = SH + 32768;
        #pragma unroll
        for (int n = 0; n < 4; ++n) {
            int f = nq * 64 + n * 16 + qc;
            float bias = qkv_b[nb * 256 + f];
            int slot = f >> 3, fin = (f & 7) * 2;
            #pragma unroll
            for (int m = 0; m < 4; ++m)
                #pragma unroll
                for (int j = 0; j < 4; ++j) {
                    int l = ph * 64 + m * 16 + g * 4 + j;
                    *(_Float16*)(eL + l * 512 + ((slot ^ (l & 7)) << 4) + fin) =
                        (_Float16)((acc[m][n][j] + bias) * scale);
                }
        }
        __syncthreads();
        _Float16* dstb = (nb == 0) ? qh : kh;
        #pragma unroll
        for (int r = 0; r < 8; ++r) {
            int s = r * 512 + tid;            // 4096 slots of 16B
            int h = s >> 9, l = (s >> 2) & 127, p = s & 3;
            uint4 vdat = *(const uint4*)(eL + l * 512 + (((h * 4 + p) ^ (l & 7)) << 4));
            int gw = gw0 + (l >> 6);
            *(uint4*)(dstb + ((size_t)(gw * 8 + h) * 64 + (l & 63)) * 32 + p * 8) = vdat;
        }
    }
}

// ---------------------------------------------------------------------------
// Fused attention + proj (unchanged from round 10).
// ---------------------------------------------------------------------------
__global__ __launch_bounds__(512, 4) void attn_proj_kernel(
    const _Float16* __restrict__ qh, const _Float16* __restrict__ kh,
    const _Float16* __restrict__ vt, const float* __restrict__ rel_bias,
    const _Float16* __restrict__ pwh, const float* __restrict__ proj_b,
    _Float16* __restrict__ feath) {

    __shared__ __align__(16) char SH[65536];
    int n = blockIdx.x;
    int win = n & 63;
    int wy = win >> 3, wx = win & 7;
    int tid = threadIdx.x, lane = tid & 63, h = tid >> 6;
    int qc = lane & 15, g = lane >> 4;
    char* P = SH + h * 8192;

    const _Float16* qp = qh + (size_t)(n * 8 + h) * 2048;
    const _Float16* kp = kh + (size_t)(n * 8 + h) * 2048;
    const _Float16* vp = vt + (size_t)(n * 8 + h) * 2048;
    const float* rb = rel_bias + (size_t)h * 4096;

    int rk[16];
    #pragma unroll
    for (int mt = 0; mt < 4; ++mt)
        #pragma unroll
        for (int j = 0; j < 4; ++j) {
            int key = mt * 16 + g * 4 + j;
            int rh = wy * 8 + (key >> 3), rw = wx * 8 + (key & 7);
            rk[mt * 4 + j] = (rh < 56 ? 0 : (rh < 60 ? 1 : 2)) * 3
                           + (rw < 56 ? 0 : (rw < 60 ? 1 : 2));
        }

    f16x8 kf[4];
    #pragma unroll
    for (int mt = 0; mt < 4; ++mt)
        kf[mt] = *(const f16x8*)(kp + (mt * 16 + qc) * 32 + g * 8);

    #pragma unroll
    for (int nt = 0; nt < 4; ++nt) {
        int q = nt * 16 + qc;
        int rqh = wy * 8 + (q >> 3), rqw = wx * 8 + (q & 7);
        int rq = (rqh < 56 ? 0 : (rqh < 60 ? 1 : 2)) * 3
               + (rqw < 56 ? 0 : (rqw < 60 ? 1 : 2));
        f16x8 qf = *(const f16x8*)(qp + q * 32 + g * 8);

        f32x4 s[4];
        #pragma unroll
        for (int mt = 0; mt < 4; ++mt) {
            f32x4 z = {0.0f, 0.0f, 0.0f, 0.0f};
            s[mt] = __builtin_amdgcn_mfma_f32_16x16x32_f16(kf[mt], qf, z, 0, 0, 0);
        }

        float vals[16];
        #pragma unroll
        for (int mt = 0; mt < 4; ++mt) {
            float4 bv4 = *(const float4*)(rb + q * 64 + mt * 16 + g * 4);
            vals[mt * 4 + 0] = s[mt][0] + bv4.x + (rk[mt * 4 + 0] != rq ? -100.0f : 0.0f);
            vals[mt * 4 + 1] = s[mt][1] + bv4.y + (rk[mt * 4 + 1] != rq ? -100.0f : 0.0f);
            vals[mt * 4 + 2] = s[mt][2] + bv4.z + (rk[mt * 4 + 2] != rq ? -100.0f : 0.0f);
            vals[mt * 4 + 3] = s[mt][3] + bv4.w + (rk[mt * 4 + 3] != rq ? -100.0f : 0.0f);
        }

        float mx = vals[0];
        #pragma unroll
        for (int i = 1; i < 16; ++i) mx = fmaxf(mx, vals[i]);
        mx = fmaxf(mx, __shfl_xor(mx, 16));
        mx = fmaxf(mx, __shfl_xor(mx, 32));

        float sum = 0.0f;
        #pragma unroll
        for (int i = 0; i < 16; ++i) { vals[i] = __expf(vals[i] - mx); sum += vals[i]; }
        sum += __shfl_xor(sum, 16);
        sum += __shfl_xor(sum, 32);
        float inv = 1.0f / sum;

        #pragma unroll
        for (int mt = 0; mt < 4; ++mt) {
            union { _Float16 x[4]; uint2 u; } pk4;
            #pragma unroll
            for (int j = 0; j < 4; ++j) pk4.x[j] = (_Float16)(vals[mt * 4 + j] * inv);
            int off = (mt * 32 + g * 8) ^ ((q & 7) << 4);
            *(uint2*)(P + q * 128 + off) = pk4.u;
        }
    }

    f16x8 pa[4][2];
    #pragma unroll
    for (int im = 0; im < 4; ++im)
        #pragma unroll
        for (int ks = 0; ks < 2; ++ks) {
            int row = im * 16 + qc;
            int off = (ks * 64 + g * 16) ^ ((row & 7) << 4);
            pa[im][ks] = *(const f16x8*)(P + row * 128 + off);
        }
    f16x8 bvv[2][2];
    #pragma unroll
    for (int in = 0; in < 2; ++in)
        #pragma unroll
        for (int ks = 0; ks < 2; ++ks)
            bvv[in][ks] = *(const f16x8*)(vp + (in * 16 + qc) * 64 + ks * 32 + g * 8);

    f32x4 acc[4][2];
    #pragma unroll
    for (int im = 0; im < 4; ++im)
        #pragma unroll
        for (int in = 0; in < 2; ++in) {
            f32x4 z = {0.0f, 0.0f, 0.0f, 0.0f};
            acc[im][in] = z;
        }
    #pragma unroll
    for (int im = 0; im < 4; ++im)
        #pragma unroll
        for (int in = 0; in < 2; ++in) {
            acc[im][in] = __builtin_amdgcn_mfma_f32_16x16x32_f16(pa[im][0], bvv[in][0], acc[im][in], 0, 0, 0);
            acc[im][in] = __builtin_amdgcn_mfma_f32_16x16x32_f16(pa[im][1], bvv[in][1], acc[im][in], 0, 0, 0);
        }

    __syncthreads();

    char* aob = SH;
    char* Bsb = SH + 32768;
    #pragma unroll
    for (int im = 0; im < 4; ++im)
        #pragma unroll
        for (int in = 0; in < 2; ++in)
            #pragma unroll
            for (int j = 0; j < 4; ++j) {
                int row = im * 16 + g * 4 + j;
                int f = h * 32 + in * 16 + qc;
                *(_Float16*)(aob + row * 512 + ((((f >> 3) ^ (row & 7)) << 4) + (f & 7) * 2)) =
                    (_Float16)acc[im][in][j];
            }
    __syncthreads();

    int w04 = h & 3, wm = h >> 2;
    const char* wcp = (const char*)pwh;
    int bidx = n >> 6;

    f32x4 pacc[2][4];
    #pragma unroll
    for (int m = 0; m < 2; ++m)
        #pragma unroll
        for (int nn = 0; nn < 4; ++nn) {
            f32x4 z = {0.0f, 0.0f, 0.0f, 0.0f};
            pacc[m][nn] = z;
        }

    for (int c = 0; c < 4; ++c) {
        #pragma unroll
        for (int r = 0; r < 4; ++r) {
            int pos = r * 512 + tid;
            int nr = pos >> 3, uu = pos & 7;
            const char* src = wcp + (size_t)nr * 512 + c * 128 + ((uu ^ (nr & 7)) << 4);
            __builtin_amdgcn_global_load_lds(
                (const __attribute__((address_space(1))) unsigned int*)src,
                (__attribute__((address_space(3))) unsigned int*)(Bsb + pos * 16),
                16, 0, 0);
        }
        __syncthreads();

        f16x8 av2[2][2], bv2[4][2];
        #pragma unroll
        for (int m = 0; m < 2; ++m) {
            int row = wm * 32 + m * 16 + qc;
            #pragma unroll
            for (int ks = 0; ks < 2; ++ks) {
                int u = c * 8 + ks * 4 + g;
                av2[m][ks] = *(const f16x8*)(aob + row * 512 + ((u ^ (row & 7)) << 4));
            }
        }
        #pragma unroll
        for (int nn = 0; nn < 4; ++nn) {
            int oc = w04 * 64 + nn * 16 + qc;
            #pragma unroll
            for (int ks = 0; ks < 2; ++ks)
                bv2[nn][ks] = *(const f16x8*)(Bsb + oc * 128 + (((ks * 4 + g) ^ (oc & 7)) << 4));
        }
        #pragma unroll
        for (int m = 0; m < 2; ++m)
            #pragma unroll
            for (int nn = 0; nn < 4; ++nn) {
                pacc[m][nn] = __builtin_amdgcn_mfma_f32_16x16x32_f16(av2[m][0], bv2[nn][0], pacc[m][nn], 0, 0, 0);
                pacc[m][nn] = __builtin_amdgcn_mfma_f32_16x16x32_f16(av2[m][1], bv2[nn][1], pacc[m][nn], 0, 0, 0);
            }
        __syncthreads();
    }

    #pragma unroll
    for (int nn = 0; nn < 4; ++nn) {
        int f = w04 * 64 + nn * 16 + qc;
        float bias = proj_b[f];
        #pragma unroll
        for (int m = 0; m < 2; ++m) {
            #pragma unroll
            for (int j = 0; j < 4; ++j) {
                int px = wm * 32 + m * 16 + g * 4 + j;
                int rh = ((win >> 3) << 3) + (px >> 3);
                int rw = ((win & 7) << 3) + (px & 7);
                int p = (rh + 4) & 63;
                int qq = (rw + 4) & 63;
                feath[((size_t)(bidx * 64 + p) * 64 + qq) * 256 + f] =
                    (_Float16)(pacc[m][nn][j] + bias);
            }
        }
    }
}

// ---------------------------------------------------------------------------
// Fused bilinear-sample + conv, f16 MFMA implicit GEMM, v4 (unchanged).
// ---------------------------------------------------------------------------
__global__ __launch_bounds__(512) void sample_conv_mfma4_kernel(
    const _Float16* __restrict__ feath, const float* __restrict__ ymap,
    const _Float16* __restrict__ wT2h, const float* __restrict__ dsc_b,
    float* __restrict__ out) {

    __shared__ __align__(16) char Ab[2][16384];   // 128 px * 128B
    __shared__ __align__(16) char Bb[2][32768];   // 256 oc * 128B
    __shared__ unsigned row0[2][9][64];
    __shared__ unsigned row1[2][9][64];
    __shared__ float    wyv[2][9][64];

    int blk = blockIdx.x;              // 0..255; XCD swizzle
    int b = blk & 7, wd0 = (blk >> 3) * 2;
    int tid = threadIdx.x;
    int lane = tid & 63, w = tid >> 6;
    int qc = lane & 15, g = lane >> 4;
    int ph = w >> 2, nq = w & 3;       // px half, oc quarter

    for (int idx = tid; idx < 1152; idx += 512) {
        int wdl = idx / 576;
        int r = idx - wdl * 576;
        int k = r >> 6, hd = r & 63;
        int wd = wd0 + wdl;
        float y = ymap[((size_t)(b * 576 + wd * 9 + k)) * 64 + hd];
        y = fminf(fmaxf(y, 0.0f), 63.0f);
        float y0f = floorf(y);
        int y0 = (int)y0f;
        int y1 = min(y0 + 1, 63);
        int xc = min(max(hd + k - 4, 0), 63);
        row0[wdl][k][hd] = (unsigned)(((b * 64 + y0) * 64 + xc) * 512);
        row1[wdl][k][hd] = (unsigned)(((b * 64 + y1) * 64 + xc) * 512);
        wyv[wdl][k][hd] = y - y0f;
    }

    f32x4 acc[4][4];
    #pragma unroll
    for (int m = 0; m < 4; ++m)
        #pragma unroll
        for (int n = 0; n < 4; ++n) {
            f32x4 z = {0.0f, 0.0f, 0.0f, 0.0f};
            acc[m][n] = z;
        }

    const char* featc = (const char*)feath;
    const char* wc    = (const char*)wT2h;

    int pxA[2], sAv[2];
    #pragma unroll
    for (int r = 0; r < 2; ++r) {
        int pos = r * 512 + tid;
        pxA[r] = pos >> 3;
        sAv[r] = pos & 7;
    }

    int rAa = qc * 128;
    int u0 = ((g    ) ^ (qc & 7)) << 4;
    int u1 = ((4 + g) ^ (qc & 7)) << 4;

    __syncthreads();

    #pragma unroll
    for (int r = 0; r < 4; ++r) {
        int pos = r * 512 + tid;
        int n = pos >> 3, uu = pos & 7;
        const char* src = wc + n * 4608 + 0 * 128 + ((uu ^ (n & 7)) << 4);
        __builtin_amdgcn_global_load_lds(
            (const __attribute__((address_space(1))) unsigned int*)src,
            (__attribute__((address_space(3))) unsigned int*)(Bb[0] + pos * 16),
            16, 0, 0);
    }
    #pragma unroll
    for (int r = 0; r < 2; ++r) {
        int px = pxA[r], sA = sAv[r];
        int wdl = px >> 6, hd = px & 63;
        unsigned b0 = row0[wdl][0][hd] + sA * 16;
        unsigned b1 = row1[wdl][0][hd] + sA * 16;
        float wy = wyv[wdl][0][hd];
        f16x8 v0 = *(const f16x8*)(featc + b0);
        f16x8 v1 = *(const f16x8*)(featc + b1);
        _Float16 wyh = (_Float16)wy;
        _Float16 omh = (_Float16)(1.0f - wy);
        f16x8 res = v0 * omh + v1 * wyh;
        *(f16x8*)(Ab[0] + px * 128 + ((sA ^ (px & 7)) << 4)) = res;
    }
    __syncthreads();

    for (int c = 0; c < 36; ++c) {
        int cur = c & 1, nxt = cur ^ 1;

        f16x8 s0[2], s1[2];
        float swy[2];
        if (c < 35) {
            int cn = c + 1;
            int ks = cn >> 2, cib = (cn & 3) * 128;
            #pragma unroll
            for (int r = 0; r < 4; ++r) {
                int pos = r * 512 + tid;
                int n = pos >> 3, uu = pos & 7;
                const char* src = wc + n * 4608 + cn * 128 + ((uu ^ (n & 7)) << 4);
                __builtin_amdgcn_global_load_lds(
                    (const __attribute__((address_space(1))) unsigned int*)src,
                    (__attribute__((address_space(3))) unsigned int*)(Bb[nxt] + pos * 16),
                    16, 0, 0);
            }
            #pragma unroll
            for (int r = 0; r < 2; ++r) {
                int px = pxA[r], sA = sAv[r];
                int wdl = px >> 6, hd = px & 63;
                unsigned b0 = row0[wdl][ks][hd] + cib + sA * 16;
                unsigned b1 = row1[wdl][ks][hd] + cib + sA * 16;
                swy[r] = wyv[wdl][ks][hd];
                s0[r] = *(const f16x8*)(featc + b0);
                s1[r] = *(const f16x8*)(featc + b1);
            }
        }

        f16x8 av[4][2], bv[4][2];
        #pragma unroll
        for (int m = 0; m < 4; ++m) {
            char* abase = Ab[cur] + ph * 8192 + m * 2048 + rAa;
            av[m][0] = *(const f16x8*)(abase + u0);
            av[m][1] = *(const f16x8*)(abase + u1);
        }
        #pragma unroll
        for (int n = 0; n < 4; ++n) {
            char* bbase = Bb[cur] + nq * 8192 + n * 2048 + rAa;
            bv[n][0] = *(const f16x8*)(bbase + u0);
            bv[n][1] = *(const f16x8*)(bbase + u1);
        }
        #pragma unroll
        for (int m = 0; m < 4; ++m)
            #pragma unroll
            for (int n = 0; n < 4; ++n) {
                acc[m][n] = __builtin_amdgcn_mfma_f32_16x16x32_f16(av[m][0], bv[n][0], acc[m][n], 0, 0, 0);
                acc[m][n] = __builtin_amdgcn_mfma_f32_16x16x32_f16(av[m][1], bv[n][1], acc[m][n], 0, 0, 0);
            }

        if (c < 35) {
            #pragma unroll
            for (int r = 0; r < 2; ++r) {
                int px = pxA[r], sA = sAv[r];
                _Float16 wyh = (_Float16)swy[r];
                _Float16 omh = (_Float16)(1.0f - swy[r]);
                f16x8 res = s0[r] * omh + s1[r] * wyh;
                *(f16x8*)(Ab[nxt] + px * 128 + ((sA ^ (px & 7)) << 4)) = res;
            }
        }
        __syncthreads();
    }

    #pragma unroll
    for (int n = 0; n < 4; ++n) {
        int o = nq * 64 + n * 16 + qc;
        float bvs = dsc_b[o];
        float* orow = out + ((size_t)(b * 256 + o) * 64 + (wd0 + ph)) * 64;
        #pragma unroll
        for (int m = 0; m < 4; ++m) {
            int px = m * 16 + g * 4;
            float4 res;
            res.x = fmaxf(acc[m][n][0] + bvs, 0.0f);
            res.y = fmaxf(acc[m][n][1] + bvs, 0.0f);
            res.z = fmaxf(acc[m][n][2] + bvs, 0.0f);
            res.w = fmaxf(acc[m][n][3] + bvs, 0.0f);
            *(float4*)(orow + px) = res;
        }
    }
}

// ---------------------------------------------------------------------------
extern "C" void kernel_launch(void* const* d_in, const int* in_sizes, int n_in,
                              void* d_out, int out_size, void* d_ws, size_t ws_size,
                              hipStream_t stream) {
    (void)in_sizes; (void)n_in; (void)out_size; (void)ws_size;
    const float* x        = (const float*)d_in[0];
    const float* qkv_w    = (const float*)d_in[1];
    const float* qkv_b    = (const float*)d_in[2];
    const float* proj_w   = (const float*)d_in[3];
    const float* proj_b   = (const float*)d_in[4];
    const float* rel_bias = (const float*)d_in[5];
    const float* offset   = (const float*)d_in[6];
    const float* dsc_w    = (const float*)d_in[7];
    const float* dsc_b    = (const float*)d_in[8];
    float* out = (float*)d_out;

    unsigned short* wsu = (unsigned short*)d_ws;
    _Float16* qh = (_Float16*)wsu;                                  // 8.39M fp16
    _Float16* kh = (_Float16*)(wsu + NFLOAT_BUF);
    _Float16* vt = (_Float16*)(wsu + 2 * (size_t)NFLOAT_BUF);
    _Float16* feath = (_Float16*)(wsu + 3 * (size_t)NFLOAT_BUF);    // fp16
    unsigned short* xb      = wsu + 4 * (size_t)NFLOAT_BUF;         // bf16
    unsigned short* wb      = wsu + 5 * (size_t)NFLOAT_BUF;         // 196608 bf16
    _Float16* pwh           = (_Float16*)(wb + 196608);             // 65536 fp16
    _Float16* wT2h          = (_Float16*)((unsigned short*)pwh + 65536);  // 589824 fp16
    float* ymap = (float*)((unsigned short*)wT2h + 589824);         // 294912 f32

    prep_kernel<<<6656, 256, 0, stream>>>(x, xb, qkv_w, wb, proj_w, pwh,
                                          dsc_w, wT2h, offset, ymap);
    qkv_mfma2_kernel<<<dim3(3, 256), 512, 0, stream>>>(xb, wb, qkv_b, qh, kh, vt);
    attn_proj_kernel<<<512, 512, 0, stream>>>(qh, kh, vt, rel_bias, pwh, proj_b, feath);
    sample_conv_mfma4_kernel<<<256, 512, 0, stream>>>(feath, ymap, wT2h, dsc_b, out);
}